// Round 4
// baseline (152.479 us; speedup 1.0000x reference)
//
#include <hip/hip_runtime.h>
#include <hip/hip_fp16.h>

#define G 128

typedef _Float16 h2_t __attribute__((ext_vector_type(2)));

union U16 { uint4 u; h2_t h2[4]; };
union HV  { uint4 u; h2_t h2[4]; };
union PK2 { uint2 u; h2_t h[2]; };

__device__ __forceinline__ float dot2f(h2_t a, h2_t b, float c) {
#if __has_builtin(__builtin_amdgcn_fdot2)
    return __builtin_amdgcn_fdot2(a, b, c, false);
#else
    return c + (float)a.x * (float)b.x + (float)a.y * (float)b.y;
#endif
}

__device__ __forceinline__ float dot4(float4 a, float4 b) {
    return a.x * b.x + a.y * b.y + a.z * b.z + a.w * b.w;
}

// ---------------------------------------------------------------------------
// Kernel A: fused conv1 (3x3x3, 1->16, SAME) + relu + m0-mask + 2x2x2 maxpool.
// UNCHANGED from round 3 (verified ~15us: out of top-5).  (256,1): round-2
// showed (256,4) caps VGPR at 64 and spills the reg-staging arrays (247MB
// scratch traffic). Register staging and tight launch-bounds are exclusive.
// ---------------------------------------------------------------------------
__global__ __launch_bounds__(256, 1)
void k_conv1_pool(const float* __restrict__ x, const int* __restrict__ occ,
                  const float* __restrict__ W1,
                  __half* __restrict__ h1p, float* __restrict__ m1)
{
    // sx: (lz,ly,lx) at (lz*18+ly)*24 + lx, lx in [0,24); gx = bx*16 - 4 + lx
    __shared__ __align__(16) _Float16      sx[10 * 18 * 24];   // 8640 B
    __shared__ __align__(16) int           pacc[16 * 256];     // 16 KB [ch][cell]
    __shared__ __align__(4)  unsigned short slist[2048];       // 4 KB
    __shared__ __align__(16) h2_t          w1L[216];           // 864 B
    __shared__ __align__(4)  unsigned char sm1[256];
    __shared__ int                         scnt;

    const int bx = blockIdx.x, by = blockIdx.y;
    const int b  = blockIdx.z >> 4, zt = blockIdx.z & 15;
    const int tid = threadIdx.x;

    const int z0 = zt * 8 - 1, y0 = by * 16 - 1;
    const int base_b = b * G * G * G;

    // ---- issue ALL staging loads first (nothing dependent between them) ----
    int4   ro[5];
    float4 rx[5];
    #pragma unroll
    for (int it = 0; it < 5; ++it) {
        int c = it * 256 + tid;
        int cc = c < 1080 ? c : 1079;          // clamp: harmless duplicate load
        int row = cc / 6, seg = cc - row * 6;  // row in [0,180)
        int lz  = row / 18, ly = row - lz * 18;
        int gz = z0 + lz, gy = y0 + ly;
        int gxc = (bx << 4) - 4 + (seg << 2);
        bool inb = (unsigned)gz < 128u && (unsigned)gy < 128u && (unsigned)gxc < 128u;
        int gi = inb ? base_b + (gz * G + gy) * G + gxc : base_b;  // safe addr
        ro[it] = *(const int4*)(occ + gi);
        rx[it] = *(const float4*)(x + gi);
    }

    // ---- phase 0 LDS init (independent of the loads above) ----
    if (tid == 0) scnt = 0;
    {
        uint4 z4 = make_uint4(0u, 0u, 0u, 0u);
        uint4* p4 = (uint4*)pacc;
        p4[tid] = z4; p4[tid + 256] = z4; p4[tid + 512] = z4; p4[tid + 768] = z4;
    }
    if (tid < 64) ((unsigned*)sm1)[tid] = 0u;
    if (tid < 216) {
        float2 f = ((const float2*)W1)[tid];   // w1L[i] = (W1[2i], W1[2i+1])
        h2_t w; w.x = (_Float16)f.x; w.y = (_Float16)f.y;
        w1L[tid] = w;
    }
    __syncthreads();   // zero/init visible before list atomics & sm1 writes

    // ---- write loop: convert + LDS store + build active list in one pass ----
    #pragma unroll
    for (int it = 0; it < 5; ++it) {
        int c = it * 256 + tid;
        if (c < 1080) {
            int row = c / 6, seg = c - row * 6;
            int lz  = row / 18, ly = row - lz * 18;
            int gz = z0 + lz, gy = y0 + ly;
            int gxc = (bx << 4) - 4 + (seg << 2);
            bool inb = (unsigned)gz < 128u && (unsigned)gy < 128u && (unsigned)gxc < 128u;
            int4   o4 = ro[it];
            float4 x4 = rx[it];
            if (!inb) o4 = make_int4(1, 1, 1, 1);
            h2_t p01, p23;
            p01.x = (o4.x == 0) ? (_Float16)x4.x : (_Float16)0.f;
            p01.y = (o4.y == 0) ? (_Float16)x4.y : (_Float16)0.f;
            p23.x = (o4.z == 0) ? (_Float16)x4.z : (_Float16)0.f;
            p23.y = (o4.w == 0) ? (_Float16)x4.w : (_Float16)0.f;
            PK2 pk; pk.h[0] = p01; pk.h[1] = p23;
            *(uint2*)&sx[row * 24 + (seg << 2)] = pk.u;

            // interior chunks (lz 1..8, ly 1..16, seg 1..4) feed the list;
            // they are always fully in-bounds so o4 is real data.
            if ((unsigned)(lz - 1) < 8u && (unsigned)(ly - 1) < 16u &&
                (unsigned)(seg - 1) < 4u) {
                int mb = (o4.x == 0 ? 1 : 0) | (o4.y == 0 ? 2 : 0) |
                         (o4.z == 0 ? 4 : 0) | (o4.w == 0 ? 8 : 0);
                if (mb) {
                    int cnt  = __popc(mb);
                    int base = atomicAdd(&scnt, cnt);
                    int cz = lz - 1, cy = ly - 1, cx0v = (seg << 2) - 4;
                    int cellb = (cz >> 1) * 64 + (cy >> 1) * 8;
                    #pragma unroll
                    for (int j = 0; j < 4; ++j) {
                        if (mb & (1 << j)) {
                            slist[base++] = (unsigned short)((cz << 8) | (cy << 4) | (cx0v + j));
                            sm1[cellb + ((cx0v + j) >> 1)] = (unsigned char)1;  // benign race: all write 1
                        }
                    }
                }
            }
        }
    }
    __syncthreads();

    const int n = scnt;   // ~205 of 2048 at 10% density

    // ---- compute: one ACTIVE center per thread ----
    const h2_t zero = (h2_t)(_Float16)0.f;
    for (int kb = 0; kb < n; kb += 256) {
        const int idx = kb + tid;
        if (idx < n) {
            const int code = slist[idx];
            const int cz = code >> 8, cy = (code >> 4) & 15, cx = code & 15;
            const int sb = ((cz + 1) * 18 + (cy + 1)) * 24 + cx + 4;
            h2_t acc[8];
            #pragma unroll
            for (int c = 0; c < 8; ++c) acc[c] = zero;
            #pragma unroll
            for (int kz = 0; kz < 3; ++kz)
            #pragma unroll
            for (int ky = 0; ky < 3; ++ky)
            #pragma unroll
            for (int kx = 0; kx < 3; ++kx) {
                _Float16 v = sx[sb + (kz - 1) * 432 + (ky - 1) * 24 + (kx - 1)];
                h2_t v2 = {v, v};
                const h2_t* w = &w1L[((kz * 3 + ky) * 3 + kx) * 8];  // uniform -> broadcast
                #pragma unroll
                for (int c = 0; c < 8; ++c) acc[c] = v2 * w[c] + acc[c];
            }
            const int cell = (cz >> 1) * 64 + (cy >> 1) * 8 + (cx >> 1);
            #pragma unroll
            for (int c = 0; c < 8; ++c) {
                atomicMax(&pacc[(2 * c) * 256 + cell],
                          __float_as_int(fmaxf((float)acc[c].x, 0.f)));
                atomicMax(&pacc[(2 * c + 1) * 256 + cell],
                          __float_as_int(fmaxf((float)acc[c].y, 0.f)));
            }
        }
    }
    __syncthreads();

    // ---- epilogue: pooled cell tid -> h1p (fp16 x16) + m1 ----
    const int tx = tid & 7, ty = (tid >> 3) & 7, tz = tid >> 6;
    const int pz = zt * 4 + tz, py = by * 8 + ty, px = bx * 8 + tx;
    const int vidx = ((b * 64 + pz) * 64 + py) * 64 + px;
    HV p0, p1;
    #pragma unroll
    for (int c = 0; c < 4; ++c) {
        h2_t a, bq;
        a.x  = (_Float16)__int_as_float(pacc[(2 * c) * 256 + tid]);
        a.y  = (_Float16)__int_as_float(pacc[(2 * c + 1) * 256 + tid]);
        bq.x = (_Float16)__int_as_float(pacc[(8 + 2 * c) * 256 + tid]);
        bq.y = (_Float16)__int_as_float(pacc[(9 + 2 * c) * 256 + tid]);
        p0.h2[c] = a; p1.h2[c] = bq;
    }
    uint4* o = (uint4*)&h1p[(size_t)vidx * 16];
    o[0] = p0.u;
    o[1] = p1.u;
    m1[vidx] = sm1[tid] ? 1.f : 0.f;
}

// ---------------------------------------------------------------------------
// Kernel B: fused conv2 (3x3x3, 16->4) + relu + m1-mask + pool + FULL DECODER.
//
// ROUND-4 REWRITE. Round-3 counters: 64.2us, VALUBusy 27.6%, HBM 7%,
// Occupancy 25%, LDS 42.5KB. Arithmetic says ideal ~14us => latency-bound:
// 2-3 resident blocks/CU, serial stage->compute->decode phases, grid only
// 4 blocks/CU. (Bank-conflict counter = 9.3/read == the structural 8-cycle
// floor for wave64 x 16B — not a lever.)
//  * Region 8x8x8 -> 8x8x4: tile [2][660] = 21.1KB, total LDS ~28KB
//    -> 5 blocks/CU resident, grid 1024 -> 2048 (8/CU) => real pipelining.
//  * m1 COMPACTION (conv1-proven pattern): thread's own m1 loaded with the
//    staging loads; ballot+prefix builds <=256-entry active list (~57%
//    density at level-1) -> compute only active centers, ~43% less dot work.
//  * Pool via LDS atomicMax on relu'd f32 int-bits (>=0 => monotonic),
//    pacc[co][parent]; m2 mask via benign-race pm[parent]=1 stores.
//  * Decoder: 32 parents x (a,bb,e) = 256 threads; tconv1 part duplicated
//    across e (~100 extra fma, negligible); per-thread 2 float4 stores.
//  * No min-waves launch-bounds (round-2 spill lesson); reg-staging 6 uint4.
// ---------------------------------------------------------------------------
__global__ __launch_bounds__(256)
void k_conv2_dec(const __half* __restrict__ h1p, const float* __restrict__ m1,
                 const float* __restrict__ W2,
                 const float* __restrict__ Wt1, const float* __restrict__ Wt2,
                 float* __restrict__ out)
{
    __shared__ uint4  tile[1320];     // [half][6*10*11] = 21.1 KB
    __shared__ float4 wt1[128];       // Wt1: 512 floats
    __shared__ float4 wt2[32];        // Wt2: 128 floats
    __shared__ __align__(16) h2_t w2L[864];   // 3456 B
    __shared__ int    pacc[128];      // [co][parent] pooled relu'd f32 bits
    __shared__ int    pm[32];         // m2 per parent
    __shared__ unsigned char slist[256];
    __shared__ int    scnt;

    const int bx = blockIdx.x, by = blockIdx.y;
    const int b  = blockIdx.z >> 4, bz = blockIdx.z & 15;
    const int tid = threadIdx.x;

    const int z0 = bz * 4 - 1, y0 = by * 8 - 1, x0 = bx * 8 - 1;

    // ---- issue all tile loads first (reg-staged, max MLP) ----
    uint4 ra[3], rb4[3];
    #pragma unroll
    for (int it = 0; it < 3; ++it) {
        int g = it * 256 + tid;
        int gg = g < 660 ? g : 659;
        int z = gg / 110, r = gg - z * 110, y = r / 11, xx = r - y * 11;
        int gz = z0 + z, gy = y0 + y, gx = x0 + xx;
        bool inb = (unsigned)gz < 64u && (unsigned)gy < 64u && (unsigned)gx < 64u;
        size_t vi = inb ? (size_t)(((b * 64 + gz) * 64 + gy) * 64 + gx) : 0;
        const uint4* src = (const uint4*)&h1p[vi * 16];
        ra[it]  = src[0];
        rb4[it] = src[1];
    }

    // own output voxel's m1 (issued with the tile loads; used for the list)
    const int cx_ = tid & 7, cy_ = (tid >> 3) & 7, cz_ = tid >> 6;
    const float mv = m1[((b * 64 + (bz * 4 + cz_)) * 64 + (by * 8 + cy_)) * 64
                        + (bx * 8 + cx_)];

    // ---- weights + small-state init (latency hides under loads above) ----
    if (tid == 0) scnt = 0;
    if (tid < 128) { wt1[tid] = ((const float4*)Wt1)[tid]; pacc[tid] = 0; }
    if (tid < 32)  { wt2[tid] = ((const float4*)Wt2)[tid]; pm[tid] = 0; }
    #pragma unroll
    for (int it = 0; it < 4; ++it) {
        int i = it * 256 + tid;
        if (i < 864) {
            int t = i >> 5, rr = i & 31, co = rr >> 3, p = rr & 7;
            h2_t w;
            w.x = (_Float16)W2[t * 64 + (2 * p) * 4 + co];
            w.y = (_Float16)W2[t * 64 + (2 * p + 1) * 4 + co];
            w2L[i] = w;
        }
    }
    __syncthreads();   // init visible before list atomics / pm stores

    // ---- tile write + active-list build ----
    #pragma unroll
    for (int it = 0; it < 3; ++it) {
        int g = it * 256 + tid;
        if (g < 660) {
            int z = g / 110, r = g - z * 110, y = r / 11, xx = r - y * 11;
            int gz = z0 + z, gy = y0 + y, gx = x0 + xx;
            bool inb = (unsigned)gz < 64u && (unsigned)gy < 64u && (unsigned)gx < 64u;
            uint4 a0 = ra[it], a1 = rb4[it];
            if (!inb) { a0 = make_uint4(0u, 0u, 0u, 0u); a1 = a0; }
            tile[g]       = a0;
            tile[660 + g] = a1;
        }
    }
    {
        const int lane = tid & 63;
        bool act = (mv != 0.f);
        unsigned long long bal = __ballot(act);
        int wtot = __popcll(bal);
        int wbase = 0;
        if (lane == 0 && wtot) wbase = atomicAdd(&scnt, wtot);
        wbase = __shfl(wbase, 0);
        if (act) {
            int pre = __popcll(bal & ((1ull << lane) - 1ull));
            slist[wbase + pre] = (unsigned char)tid;
            pm[(cz_ >> 1) * 16 + (cy_ >> 1) * 4 + (cx_ >> 1)] = 1;  // benign race
        }
    }
    __syncthreads();

    const int n = scnt;   // ~146 of 256 at 57% level-1 density

    // ---- compute: one ACTIVE conv output per thread (4 out channels) ----
    if (tid < n) {
        const int code = slist[tid];
        const int cx = code & 7, cy = (code >> 3) & 7, cz = code >> 6;
        float acc[4] = {0.f, 0.f, 0.f, 0.f};
        #pragma unroll
        for (int kz = 0; kz < 3; ++kz)
        #pragma unroll
        for (int ky = 0; ky < 3; ++ky) {
            const int rb = ((cz + kz) * 10 + (cy + ky)) * 11 + cx;
            h2_t hp[2][3][4];
            #pragma unroll
            for (int hh = 0; hh < 2; ++hh)
            #pragma unroll
            for (int xi = 0; xi < 3; ++xi) {
                U16 a; a.u = tile[hh * 660 + rb + xi];
                #pragma unroll
                for (int p = 0; p < 4; ++p) hp[hh][xi][p] = a.h2[p];
            }
            const int t3 = (kz * 3 + ky) * 3;
            #pragma unroll
            for (int kx = 0; kx < 3; ++kx) {
                const h2_t* w = &w2L[(t3 + kx) * 32];   // uniform -> broadcast
                #pragma unroll
                for (int co = 0; co < 4; ++co) {
                    float a = acc[co];
                    #pragma unroll
                    for (int hh = 0; hh < 2; ++hh)
                    #pragma unroll
                    for (int p = 0; p < 4; ++p)
                        a = dot2f(hp[hh][kx][p], w[co * 8 + 4 * hh + p], a);
                    acc[co] = a;
                }
            }
        }
        // active => m1 == 1 exactly, so gated value is just relu(acc)
        const int parent = (cz >> 1) * 16 + (cy >> 1) * 4 + (cx >> 1);
        #pragma unroll
        for (int co = 0; co < 4; ++co)
            atomicMax(&pacc[co * 32 + parent],
                      __float_as_int(fmaxf(acc[co], 0.f)));
    }
    __syncthreads();

    // ---- decoder: thread = (parent p, a, bb, e); f looped ----
    {
        const int p  = tid >> 3;
        const int a  = (tid >> 2) & 1;
        const int bb = (tid >> 1) & 1;
        const int e  = tid & 1;
        const int pZ = p >> 4, pY = (p >> 2) & 3, pq = p & 3;
        const int pz = bz * 2 + pZ, py = by * 4 + pY, pxq = bx * 4 + pq;

        const float mm = pm[p] ? 1.f : 0.f;
        const float4 hv = make_float4(__int_as_float(pacc[p]),
                                      __int_as_float(pacc[32 + p]),
                                      __int_as_float(pacc[64 + p]),
                                      __int_as_float(pacc[96 + p]));

        const int b0q = ((((1 - a) * 2 + (1 - bb)) * 2) + 1) * 16;  // c=0 -> kc=1
        const int b1q = ((((1 - a) * 2 + (1 - bb)) * 2) + 0) * 16;  // c=1 -> kc=0
        float4 t0q[4], t1q[4];
        #pragma unroll
        for (int q = 0; q < 4; ++q) {
            float4 a0 = wt1[b0q + q],      a1 = wt1[b0q + 4 + q];
            float4 a2 = wt1[b0q + 8 + q],  a3 = wt1[b0q + 12 + q];
            float4 c0 = wt1[b1q + q],      c1 = wt1[b1q + 4 + q];
            float4 c2 = wt1[b1q + 8 + q],  c3 = wt1[b1q + 12 + q];
            float4 s0, s1;
            s0.x = hv.x * a0.x + hv.y * a1.x + hv.z * a2.x + hv.w * a3.x;
            s0.y = hv.x * a0.y + hv.y * a1.y + hv.z * a2.y + hv.w * a3.y;
            s0.z = hv.x * a0.z + hv.y * a1.z + hv.z * a2.z + hv.w * a3.z;
            s0.w = hv.x * a0.w + hv.y * a1.w + hv.z * a2.w + hv.w * a3.w;
            s1.x = hv.x * c0.x + hv.y * c1.x + hv.z * c2.x + hv.w * c3.x;
            s1.y = hv.x * c0.y + hv.y * c1.y + hv.z * c2.y + hv.w * c3.y;
            s1.z = hv.x * c0.z + hv.y * c1.z + hv.z * c2.z + hv.w * c3.z;
            s1.w = hv.x * c0.w + hv.y * c1.w + hv.z * c2.w + hv.w * c3.w;
            t0q[q] = make_float4(fmaxf(s0.x, 0.f), fmaxf(s0.y, 0.f),
                                 fmaxf(s0.z, 0.f), fmaxf(s0.w, 0.f));
            t1q[q] = make_float4(fmaxf(s1.x, 0.f), fmaxf(s1.y, 0.f),
                                 fmaxf(s1.z, 0.f), fmaxf(s1.w, 0.f));
        }

        const int d = 4 * pz + 2 * a + e;
        #pragma unroll
        for (int f = 0; f < 2; ++f) {
            const int hh = 4 * py + 2 * bb + f;
            const int be = ((1 - e) * 2 + (1 - f)) * 2;
            const float4* wg0 = &wt2[(be + 1) * 4];   // g=0 -> kg=1
            const float4* wg1 = &wt2[(be + 0) * 4];   // g=1 -> kg=0
            float s00 = dot4(t0q[0], wg0[0]) + dot4(t0q[1], wg0[1])
                      + dot4(t0q[2], wg0[2]) + dot4(t0q[3], wg0[3]);
            float s01 = dot4(t0q[0], wg1[0]) + dot4(t0q[1], wg1[1])
                      + dot4(t0q[2], wg1[2]) + dot4(t0q[3], wg1[3]);
            float s10 = dot4(t1q[0], wg0[0]) + dot4(t1q[1], wg0[1])
                      + dot4(t1q[2], wg0[2]) + dot4(t1q[3], wg0[3]);
            float s11 = dot4(t1q[0], wg1[0]) + dot4(t1q[1], wg1[1])
                      + dot4(t1q[2], wg1[2]) + dot4(t1q[3], wg1[3]);
            float4 o;
            o.x = mm / (1.f + __expf(-s00));
            o.y = mm / (1.f + __expf(-s01));
            o.z = mm / (1.f + __expf(-s10));
            o.w = mm / (1.f + __expf(-s11));
            *(float4*)&out[((b * G + d) * G + hh) * G + 4 * pxq] = o;
        }
    }
}

extern "C" void kernel_launch(void* const* d_in, const int* in_sizes, int n_in,
                              void* d_out, int out_size, void* d_ws, size_t ws_size,
                              hipStream_t stream) {
    (void)in_sizes; (void)n_in; (void)out_size; (void)ws_size;
    const float* x   = (const float*)d_in[0];
    const float* W1  = (const float*)d_in[1];
    const float* W2  = (const float*)d_in[2];
    const float* Wt1 = (const float*)d_in[3];
    const float* Wt2 = (const float*)d_in[4];
    const int*   occ = (const int*)d_in[5];
    float* out = (float*)d_out;

    char* ws = (char*)d_ws;
    __half* h1p = (__half*)ws;                                  // 16 MB
    float*  m1  = (float*)(ws + 8388608ull * sizeof(__half));   // 2 MB

    k_conv1_pool<<<dim3(8, 8, 32), dim3(256), 0, stream>>>(x, occ, W1, h1p, m1);
    k_conv2_dec<<<dim3(8, 8, 32), dim3(256), 0, stream>>>(h1p, m1, W2, Wt1, Wt2, out);
}

// Round 5
// 150.978 us; speedup vs baseline: 1.0099x; 1.0099x over previous
//
#include <hip/hip_runtime.h>
#include <hip/hip_fp16.h>

#define G 128

typedef _Float16 h2_t __attribute__((ext_vector_type(2)));

union U16 { uint4 u; h2_t h2[4]; };
union HV  { uint4 u; h2_t h2[4]; };
union PK2 { uint2 u; h2_t h[2]; };

__device__ __forceinline__ float dot2f(h2_t a, h2_t b, float c) {
#if __has_builtin(__builtin_amdgcn_fdot2)
    return __builtin_amdgcn_fdot2(a, b, c, false);
#else
    return c + (float)a.x * (float)b.x + (float)a.y * (float)b.y;
#endif
}

__device__ __forceinline__ float dot4(float4 a, float4 b) {
    return a.x * b.x + a.y * b.y + a.z * b.z + a.w * b.w;
}

// ---------------------------------------------------------------------------
// Kernel A: fused conv1 (3x3x3, 1->16, SAME) + relu + m0-mask + 2x2x2 maxpool.
// UNCHANGED (byte-identical) since round 3 — measured out-of-top-5.
// (256,1): round-2 showed (256,4) caps VGPR at 64 and spills the reg-staging
// arrays (247MB scratch traffic). Reg staging + tight bounds are exclusive.
// ---------------------------------------------------------------------------
__global__ __launch_bounds__(256, 1)
void k_conv1_pool(const float* __restrict__ x, const int* __restrict__ occ,
                  const float* __restrict__ W1,
                  __half* __restrict__ h1p, float* __restrict__ m1)
{
    // sx: (lz,ly,lx) at (lz*18+ly)*24 + lx, lx in [0,24); gx = bx*16 - 4 + lx
    __shared__ __align__(16) _Float16      sx[10 * 18 * 24];   // 8640 B
    __shared__ __align__(16) int           pacc[16 * 256];     // 16 KB [ch][cell]
    __shared__ __align__(4)  unsigned short slist[2048];       // 4 KB
    __shared__ __align__(16) h2_t          w1L[216];           // 864 B
    __shared__ __align__(4)  unsigned char sm1[256];
    __shared__ int                         scnt;

    const int bx = blockIdx.x, by = blockIdx.y;
    const int b  = blockIdx.z >> 4, zt = blockIdx.z & 15;
    const int tid = threadIdx.x;

    const int z0 = zt * 8 - 1, y0 = by * 16 - 1;
    const int base_b = b * G * G * G;

    // ---- issue ALL staging loads first (nothing dependent between them) ----
    int4   ro[5];
    float4 rx[5];
    #pragma unroll
    for (int it = 0; it < 5; ++it) {
        int c = it * 256 + tid;
        int cc = c < 1080 ? c : 1079;          // clamp: harmless duplicate load
        int row = cc / 6, seg = cc - row * 6;  // row in [0,180)
        int lz  = row / 18, ly = row - lz * 18;
        int gz = z0 + lz, gy = y0 + ly;
        int gxc = (bx << 4) - 4 + (seg << 2);
        bool inb = (unsigned)gz < 128u && (unsigned)gy < 128u && (unsigned)gxc < 128u;
        int gi = inb ? base_b + (gz * G + gy) * G + gxc : base_b;  // safe addr
        ro[it] = *(const int4*)(occ + gi);
        rx[it] = *(const float4*)(x + gi);
    }

    // ---- phase 0 LDS init (independent of the loads above) ----
    if (tid == 0) scnt = 0;
    {
        uint4 z4 = make_uint4(0u, 0u, 0u, 0u);
        uint4* p4 = (uint4*)pacc;
        p4[tid] = z4; p4[tid + 256] = z4; p4[tid + 512] = z4; p4[tid + 768] = z4;
    }
    if (tid < 64) ((unsigned*)sm1)[tid] = 0u;
    if (tid < 216) {
        float2 f = ((const float2*)W1)[tid];   // w1L[i] = (W1[2i], W1[2i+1])
        h2_t w; w.x = (_Float16)f.x; w.y = (_Float16)f.y;
        w1L[tid] = w;
    }
    __syncthreads();   // zero/init visible before list atomics & sm1 writes

    // ---- write loop: convert + LDS store + build active list in one pass ----
    #pragma unroll
    for (int it = 0; it < 5; ++it) {
        int c = it * 256 + tid;
        if (c < 1080) {
            int row = c / 6, seg = c - row * 6;
            int lz  = row / 18, ly = row - lz * 18;
            int gz = z0 + lz, gy = y0 + ly;
            int gxc = (bx << 4) - 4 + (seg << 2);
            bool inb = (unsigned)gz < 128u && (unsigned)gy < 128u && (unsigned)gxc < 128u;
            int4   o4 = ro[it];
            float4 x4 = rx[it];
            if (!inb) o4 = make_int4(1, 1, 1, 1);
            h2_t p01, p23;
            p01.x = (o4.x == 0) ? (_Float16)x4.x : (_Float16)0.f;
            p01.y = (o4.y == 0) ? (_Float16)x4.y : (_Float16)0.f;
            p23.x = (o4.z == 0) ? (_Float16)x4.z : (_Float16)0.f;
            p23.y = (o4.w == 0) ? (_Float16)x4.w : (_Float16)0.f;
            PK2 pk; pk.h[0] = p01; pk.h[1] = p23;
            *(uint2*)&sx[row * 24 + (seg << 2)] = pk.u;

            // interior chunks (lz 1..8, ly 1..16, seg 1..4) feed the list;
            // they are always fully in-bounds so o4 is real data.
            if ((unsigned)(lz - 1) < 8u && (unsigned)(ly - 1) < 16u &&
                (unsigned)(seg - 1) < 4u) {
                int mb = (o4.x == 0 ? 1 : 0) | (o4.y == 0 ? 2 : 0) |
                         (o4.z == 0 ? 4 : 0) | (o4.w == 0 ? 8 : 0);
                if (mb) {
                    int cnt  = __popc(mb);
                    int base = atomicAdd(&scnt, cnt);
                    int cz = lz - 1, cy = ly - 1, cx0v = (seg << 2) - 4;
                    int cellb = (cz >> 1) * 64 + (cy >> 1) * 8;
                    #pragma unroll
                    for (int j = 0; j < 4; ++j) {
                        if (mb & (1 << j)) {
                            slist[base++] = (unsigned short)((cz << 8) | (cy << 4) | (cx0v + j));
                            sm1[cellb + ((cx0v + j) >> 1)] = (unsigned char)1;  // benign race: all write 1
                        }
                    }
                }
            }
        }
    }
    __syncthreads();

    const int n = scnt;   // ~205 of 2048 at 10% density

    // ---- compute: one ACTIVE center per thread ----
    const h2_t zero = (h2_t)(_Float16)0.f;
    for (int kb = 0; kb < n; kb += 256) {
        const int idx = kb + tid;
        if (idx < n) {
            const int code = slist[idx];
            const int cz = code >> 8, cy = (code >> 4) & 15, cx = code & 15;
            const int sb = ((cz + 1) * 18 + (cy + 1)) * 24 + cx + 4;
            h2_t acc[8];
            #pragma unroll
            for (int c = 0; c < 8; ++c) acc[c] = zero;
            #pragma unroll
            for (int kz = 0; kz < 3; ++kz)
            #pragma unroll
            for (int ky = 0; ky < 3; ++ky)
            #pragma unroll
            for (int kx = 0; kx < 3; ++kx) {
                _Float16 v = sx[sb + (kz - 1) * 432 + (ky - 1) * 24 + (kx - 1)];
                h2_t v2 = {v, v};
                const h2_t* w = &w1L[((kz * 3 + ky) * 3 + kx) * 8];  // uniform -> broadcast
                #pragma unroll
                for (int c = 0; c < 8; ++c) acc[c] = v2 * w[c] + acc[c];
            }
            const int cell = (cz >> 1) * 64 + (cy >> 1) * 8 + (cx >> 1);
            #pragma unroll
            for (int c = 0; c < 8; ++c) {
                atomicMax(&pacc[(2 * c) * 256 + cell],
                          __float_as_int(fmaxf((float)acc[c].x, 0.f)));
                atomicMax(&pacc[(2 * c + 1) * 256 + cell],
                          __float_as_int(fmaxf((float)acc[c].y, 0.f)));
            }
        }
    }
    __syncthreads();

    // ---- epilogue: pooled cell tid -> h1p (fp16 x16) + m1 ----
    const int tx = tid & 7, ty = (tid >> 3) & 7, tz = tid >> 6;
    const int pz = zt * 4 + tz, py = by * 8 + ty, px = bx * 8 + tx;
    const int vidx = ((b * 64 + pz) * 64 + py) * 64 + px;
    HV p0, p1;
    #pragma unroll
    for (int c = 0; c < 4; ++c) {
        h2_t a, bq;
        a.x  = (_Float16)__int_as_float(pacc[(2 * c) * 256 + tid]);
        a.y  = (_Float16)__int_as_float(pacc[(2 * c + 1) * 256 + tid]);
        bq.x = (_Float16)__int_as_float(pacc[(8 + 2 * c) * 256 + tid]);
        bq.y = (_Float16)__int_as_float(pacc[(9 + 2 * c) * 256 + tid]);
        p0.h2[c] = a; p1.h2[c] = bq;
    }
    uint4* o = (uint4*)&h1p[(size_t)vidx * 16];
    o[0] = p0.u;
    o[1] = p1.u;
    m1[vidx] = sm1[tid] ? 1.f : 0.f;
}

// ---------------------------------------------------------------------------
// Kernel B: fused conv2 (3x3x3, 16->4) + relu + m1-mask + pool + FULL DECODER.
//
// ROUND-5 REWRITE: NO LDS INPUT TILE. Empirical pattern across rounds:
// conv2 duration tracks resident blocks/CU (~42us @6-7, ~44 @5, 64.2 @3)
// and is insensitive to VALU cuts => barrier-lockstep latency-bound.
// h1p is 16MB; each XCD's z-slab working set is 2.36MB <= 4MB XCD L2
// (Common-mistake #7: don't LDS-stage what L2 serves). So:
//  * Each ACTIVE thread reads its 27-voxel neighborhood (54 x 16B) directly
//    from global (L2-hot), software-pipelined one (kz,ky)-row ahead for MLP.
//    No tile, no stage barrier, waves self-schedule through compute.
//  * LDS holds only: w2L 3.4KB + wt1 2KB + wt2 0.5KB + pacc/pm/slist ~1KB.
//  * Bijective XCD swizzle: lin -> work (lin%8)*256 + lin/8; decode gives
//    each XCD 4 contiguous bz-slabs => slab-local L2 reuse (2.36MB/XCD).
//  * m1 compaction (ballot list, ~57% density), pool via LDS atomicMax on
//    relu'd f32 bits (>=0 => monotonic), decoder unchanged from round 4.
//  * No min-waves bound (spill lesson). Barriers: 3 total, all cheap.
// ---------------------------------------------------------------------------
__global__ __launch_bounds__(256)
void k_conv2_dec(const __half* __restrict__ h1p, const float* __restrict__ m1,
                 const float* __restrict__ W2,
                 const float* __restrict__ Wt1, const float* __restrict__ Wt2,
                 float* __restrict__ out)
{
    __shared__ float4 wt1[128];       // Wt1: 512 floats
    __shared__ float4 wt2[32];        // Wt2: 128 floats
    __shared__ __align__(16) h2_t w2L[864];   // 3456 B
    __shared__ int    pacc[128];      // [co][parent] pooled relu'd f32 bits
    __shared__ int    pm[32];         // m2 per parent
    __shared__ unsigned char slist[256];
    __shared__ int    scnt;

    const int tid = threadIdx.x;

    // ---- XCD-contiguous work decode (bijective: 2048 = 8 XCD x 256) ----
    const int lin  = blockIdx.x + 8 * (blockIdx.y + 8 * blockIdx.z);  // 0..2047
    const int wrk  = ((lin & 7) << 8) | (lin >> 3);
    const int bx   = wrk & 7, by = (wrk >> 3) & 7;
    const int zidx = wrk >> 6;               // 0..31 ; XCD k owns [4k,4k+4)
    const int b    = zidx >> 4, bz = zidx & 15;

    // ---- own output voxel's m1 (issue first; gates everything) ----
    const int cx_ = tid & 7, cy_ = (tid >> 3) & 7, cz_ = tid >> 6;
    const float mv = m1[((b * 64 + (bz * 4 + cz_)) * 64 + (by * 8 + cy_)) * 64
                        + (bx * 8 + cx_)];

    // ---- LDS init: weights + pooled state (hides under the m1 load) ----
    if (tid == 0) scnt = 0;
    if (tid < 128) { wt1[tid] = ((const float4*)Wt1)[tid]; pacc[tid] = 0; }
    if (tid < 32)  { wt2[tid] = ((const float4*)Wt2)[tid]; pm[tid] = 0; }
    #pragma unroll
    for (int it = 0; it < 4; ++it) {
        int i = it * 256 + tid;
        if (i < 864) {
            int t = i >> 5, rr = i & 31, co = rr >> 3, p = rr & 7;
            h2_t w;
            w.x = (_Float16)W2[t * 64 + (2 * p) * 4 + co];
            w.y = (_Float16)W2[t * 64 + (2 * p + 1) * 4 + co];
            w2L[i] = w;
        }
    }
    __syncthreads();   // init visible before list atomics / pm stores

    // ---- active-list build (ballot + prefix) ----
    {
        const int lane = tid & 63;
        bool act = (mv != 0.f);
        unsigned long long bal = __ballot(act);
        int wtot = __popcll(bal);
        int wbase = 0;
        if (lane == 0 && wtot) wbase = atomicAdd(&scnt, wtot);
        wbase = __shfl(wbase, 0);
        if (act) {
            int pre = __popcll(bal & ((1ull << lane) - 1ull));
            slist[wbase + pre] = (unsigned char)tid;
            pm[(cz_ >> 1) * 16 + (cy_ >> 1) * 4 + (cx_ >> 1)] = 1;  // benign race
        }
    }
    __syncthreads();

    const int n = scnt;   // ~146 of 256 at 57% level-1 density

    // ---- compute: one ACTIVE output voxel per thread, global-direct ----
    if (tid < n) {
        const int code = slist[tid];
        const int cx = code & 7, cy = (code >> 3) & 7, cz = code >> 6;
        const int gz0 = bz * 4 + cz - 1;
        const int gy0 = by * 8 + cy - 1;
        const int gx0 = bx * 8 + cx - 1;
        const __half* __restrict__ hb = h1p + ((size_t)b << 18) * 16;

        float acc[4] = {0.f, 0.f, 0.f, 0.f};

        // software pipeline: load (kz,ky) row r+1 while computing row r.
        uint4 curv[3][2], nxtv[3][2];

        // prologue: row 0
        {
            const int gz = gz0, gy = gy0;
            const bool zy = ((unsigned)gz < 64u) && ((unsigned)gy < 64u);
            #pragma unroll
            for (int xi = 0; xi < 3; ++xi) {
                const int gx = gx0 + xi;
                const bool ok = zy && ((unsigned)gx < 64u);
                const size_t vi = ok ? (size_t)((gz * 64 + gy) * 64 + gx) : 0;
                const uint4* s = (const uint4*)&hb[vi * 16];
                uint4 a0 = s[0], a1 = s[1];
                if (!ok) { a0 = make_uint4(0u,0u,0u,0u); a1 = a0; }
                curv[xi][0] = a0; curv[xi][1] = a1;
            }
        }

        #pragma unroll
        for (int r = 0; r < 9; ++r) {
            // issue next row's loads first (independent of current compute)
            if (r < 8) {
                const int rz = (r + 1) / 3, ry = (r + 1) - rz * 3;
                const int gz = gz0 + rz, gy = gy0 + ry;
                const bool zy = ((unsigned)gz < 64u) && ((unsigned)gy < 64u);
                #pragma unroll
                for (int xi = 0; xi < 3; ++xi) {
                    const int gx = gx0 + xi;
                    const bool ok = zy && ((unsigned)gx < 64u);
                    const size_t vi = ok ? (size_t)((gz * 64 + gy) * 64 + gx) : 0;
                    const uint4* s = (const uint4*)&hb[vi * 16];
                    uint4 a0 = s[0], a1 = s[1];
                    if (!ok) { a0 = make_uint4(0u,0u,0u,0u); a1 = a0; }
                    nxtv[xi][0] = a0; nxtv[xi][1] = a1;
                }
            }

            // compute current row (taps kx = 0..2 share the 3 loaded voxels)
            {
                const h2_t* wrow = &w2L[(r * 3) * 32];
                #pragma unroll
                for (int kx = 0; kx < 3; ++kx) {
                    U16 a0; a0.u = curv[kx][0];
                    U16 a1; a1.u = curv[kx][1];
                    const h2_t* wv = wrow + kx * 32;   // uniform -> broadcast
                    #pragma unroll
                    for (int co = 0; co < 4; ++co) {
                        float a = acc[co];
                        #pragma unroll
                        for (int p = 0; p < 4; ++p) {
                            a = dot2f(a0.h2[p], wv[co * 8 + p], a);
                            a = dot2f(a1.h2[p], wv[co * 8 + 4 + p], a);
                        }
                        acc[co] = a;
                    }
                }
            }

            if (r < 8) {
                #pragma unroll
                for (int xi = 0; xi < 3; ++xi) {
                    curv[xi][0] = nxtv[xi][0];
                    curv[xi][1] = nxtv[xi][1];
                }
            }
        }

        // active => m1 == 1 exactly, so gated value is just relu(acc)
        const int parent = (cz >> 1) * 16 + (cy >> 1) * 4 + (cx >> 1);
        #pragma unroll
        for (int co = 0; co < 4; ++co)
            atomicMax(&pacc[co * 32 + parent],
                      __float_as_int(fmaxf(acc[co], 0.f)));
    }
    __syncthreads();

    // ---- decoder: thread = (parent p, a, bb, e); f looped ----
    {
        const int p  = tid >> 3;
        const int a  = (tid >> 2) & 1;
        const int bb = (tid >> 1) & 1;
        const int e  = tid & 1;
        const int pZ = p >> 4, pY = (p >> 2) & 3, pq = p & 3;
        const int pz = bz * 2 + pZ, py = by * 4 + pY, pxq = bx * 4 + pq;

        const float mm = pm[p] ? 1.f : 0.f;
        const float4 hv = make_float4(__int_as_float(pacc[p]),
                                      __int_as_float(pacc[32 + p]),
                                      __int_as_float(pacc[64 + p]),
                                      __int_as_float(pacc[96 + p]));

        const int b0q = ((((1 - a) * 2 + (1 - bb)) * 2) + 1) * 16;  // c=0 -> kc=1
        const int b1q = ((((1 - a) * 2 + (1 - bb)) * 2) + 0) * 16;  // c=1 -> kc=0
        float4 t0q[4], t1q[4];
        #pragma unroll
        for (int q = 0; q < 4; ++q) {
            float4 a0 = wt1[b0q + q],      a1 = wt1[b0q + 4 + q];
            float4 a2 = wt1[b0q + 8 + q],  a3 = wt1[b0q + 12 + q];
            float4 c0 = wt1[b1q + q],      c1 = wt1[b1q + 4 + q];
            float4 c2 = wt1[b1q + 8 + q],  c3 = wt1[b1q + 12 + q];
            float4 s0, s1;
            s0.x = hv.x * a0.x + hv.y * a1.x + hv.z * a2.x + hv.w * a3.x;
            s0.y = hv.x * a0.y + hv.y * a1.y + hv.z * a2.y + hv.w * a3.y;
            s0.z = hv.x * a0.z + hv.y * a1.z + hv.z * a2.z + hv.w * a3.z;
            s0.w = hv.x * a0.w + hv.y * a1.w + hv.z * a2.w + hv.w * a3.w;
            s1.x = hv.x * c0.x + hv.y * c1.x + hv.z * c2.x + hv.w * c3.x;
            s1.y = hv.x * c0.y + hv.y * c1.y + hv.z * c2.y + hv.w * c3.y;
            s1.z = hv.x * c0.z + hv.y * c1.z + hv.z * c2.z + hv.w * c3.z;
            s1.w = hv.x * c0.w + hv.y * c1.w + hv.z * c2.w + hv.w * c3.w;
            t0q[q] = make_float4(fmaxf(s0.x, 0.f), fmaxf(s0.y, 0.f),
                                 fmaxf(s0.z, 0.f), fmaxf(s0.w, 0.f));
            t1q[q] = make_float4(fmaxf(s1.x, 0.f), fmaxf(s1.y, 0.f),
                                 fmaxf(s1.z, 0.f), fmaxf(s1.w, 0.f));
        }

        const int d = 4 * pz + 2 * a + e;
        #pragma unroll
        for (int f = 0; f < 2; ++f) {
            const int hh = 4 * py + 2 * bb + f;
            const int be = ((1 - e) * 2 + (1 - f)) * 2;
            const float4* wg0 = &wt2[(be + 1) * 4];   // g=0 -> kg=1
            const float4* wg1 = &wt2[(be + 0) * 4];   // g=1 -> kg=0
            float s00 = dot4(t0q[0], wg0[0]) + dot4(t0q[1], wg0[1])
                      + dot4(t0q[2], wg0[2]) + dot4(t0q[3], wg0[3]);
            float s01 = dot4(t0q[0], wg1[0]) + dot4(t0q[1], wg1[1])
                      + dot4(t0q[2], wg1[2]) + dot4(t0q[3], wg1[3]);
            float s10 = dot4(t1q[0], wg0[0]) + dot4(t1q[1], wg0[1])
                      + dot4(t1q[2], wg0[2]) + dot4(t1q[3], wg0[3]);
            float s11 = dot4(t1q[0], wg1[0]) + dot4(t1q[1], wg1[1])
                      + dot4(t1q[2], wg1[2]) + dot4(t1q[3], wg1[3]);
            float4 o;
            o.x = mm / (1.f + __expf(-s00));
            o.y = mm / (1.f + __expf(-s01));
            o.z = mm / (1.f + __expf(-s10));
            o.w = mm / (1.f + __expf(-s11));
            *(float4*)&out[((b * G + d) * G + hh) * G + 4 * pxq] = o;
        }
    }
}

extern "C" void kernel_launch(void* const* d_in, const int* in_sizes, int n_in,
                              void* d_out, int out_size, void* d_ws, size_t ws_size,
                              hipStream_t stream) {
    (void)in_sizes; (void)n_in; (void)out_size; (void)ws_size;
    const float* x   = (const float*)d_in[0];
    const float* W1  = (const float*)d_in[1];
    const float* W2  = (const float*)d_in[2];
    const float* Wt1 = (const float*)d_in[3];
    const float* Wt2 = (const float*)d_in[4];
    const int*   occ = (const int*)d_in[5];
    float* out = (float*)d_out;

    char* ws = (char*)d_ws;
    __half* h1p = (__half*)ws;                                  // 16 MB
    float*  m1  = (float*)(ws + 8388608ull * sizeof(__half));   // 2 MB

    k_conv1_pool<<<dim3(8, 8, 32), dim3(256), 0, stream>>>(x, occ, W1, h1p, m1);
    k_conv2_dec<<<dim3(8, 8, 32), dim3(256), 0, stream>>>(h1p, m1, W2, Wt1, Wt2, out);
}